// Round 8
// baseline (2253.955 us; speedup 1.0000x reference)
//
#include <hip/hip_runtime.h>

typedef __attribute__((ext_vector_type(4))) float f32x4;

#define B_ 8
#define H_ 8
#define N_ 2048
#define D_ 64
#define STR 68   // LDS row stride in floats: 64 data + 4 pad (272B, 16B-aligned)

__global__ __launch_bounds__(256) void attn_f32(
    const float* __restrict__ Qg, const float* __restrict__ Kg,
    const float* __restrict__ Vg, const int* __restrict__ maskg,
    float* __restrict__ Og)
{
  const int bh  = blockIdx.y;      // b*H + h, row-major (B,H,N,D)
  const int b   = bh >> 3;         // H_ == 8
  const int tid = threadIdx.x;
  const int q   = blockIdx.x * 256 + tid;   // one query row per thread

  __shared__ float sK[64 * STR];
  __shared__ float sV[64 * STR];
  __shared__ float sMt[64];

  // ---- my q row: 64 f32 in registers ----
  float qv[64];
  {
    const float* qp = Qg + ((size_t)(bh * N_ + q)) * D_;
#pragma unroll
    for (int i = 0; i < 16; ++i) {
      f32x4 t = *(const f32x4*)(qp + i * 4);
      qv[i * 4 + 0] = t.x; qv[i * 4 + 1] = t.y;
      qv[i * 4 + 2] = t.z; qv[i * 4 + 3] = t.w;
    }
  }

  float acc[64];
#pragma unroll
  for (int i = 0; i < 64; ++i) acc[i] = 0.f;
  float den = 0.f;

  const size_t kvbase = (size_t)bh * N_ * D_;

  for (int k0 = 0; k0 < N_; k0 += 64) {
    __syncthreads();  // previous tile's reads complete
    // ---- stage 64 K rows and 64 V rows (coalesced float4) ----
#pragma unroll
    for (int cc = 0; cc < 4; ++cc) {
      const int c   = tid + cc * 256;  // 0..1023
      const int row = c >> 4;          // 16 float4 per row
      const int ch  = c & 15;
      *(f32x4*)&sK[row * STR + ch * 4] =
          *(const f32x4*)(Kg + kvbase + (size_t)(k0 + row) * D_ + ch * 4);
      *(f32x4*)&sV[row * STR + ch * 4] =
          *(const f32x4*)(Vg + kvbase + (size_t)(k0 + row) * D_ + ch * 4);
    }
    if (tid < 64) sMt[tid] = maskg[b * N_ + k0 + tid] ? 0.f : 1.f;  // mask (B,N,1) int32; True = masked
    __syncthreads();

    // ---- 64 staged keys; all lanes read the same row -> LDS broadcast ----
    for (int kk = 0; kk < 64; ++kk) {
      const f32x4* kr = (const f32x4*)&sK[kk * STR];
      float dot = 0.f;
#pragma unroll
      for (int i = 0; i < 16; ++i) {
        f32x4 t = kr[i];
        dot += qv[i * 4 + 0] * t.x + qv[i * 4 + 1] * t.y +
               qv[i * 4 + 2] * t.z + qv[i * 4 + 3] * t.w;
      }
      // logit = 10*tanh(dot/8) in (-10,10); p = exp(logit-10) in (0,1]; exact
      // softmax since all logits share the -10 shift. NaN-free by construction.
      float x  = dot * 0.125f;
      float ax = fminf(fabsf(x), 20.f);
      float z  = __builtin_amdgcn_exp2f(ax * -2.8853900817779268f);  // e^{-2ax}
      float th = (1.f - z) * __builtin_amdgcn_rcpf(1.f + z);         // tanh(ax)
      float l  = (x >= 0.f) ? (10.f * th) : (-10.f * th);
      float p  = __builtin_amdgcn_exp2f((l - 10.f) * 1.4426950408889634f) * sMt[kk];
      den += p;
      const f32x4* vr = (const f32x4*)&sV[kk * STR];
#pragma unroll
      for (int i = 0; i < 16; ++i) {
        f32x4 t = vr[i];
        acc[i * 4 + 0] += p * t.x; acc[i * 4 + 1] += p * t.y;
        acc[i * 4 + 2] += p * t.z; acc[i * 4 + 3] += p * t.w;
      }
    }
  }

  const float inv = (den > 0.f) ? (1.f / den) : 0.f;
  float* op = Og + ((size_t)(bh * N_ + q)) * D_;
#pragma unroll
  for (int i = 0; i < 16; ++i) {
    f32x4 t;
    t.x = acc[i * 4 + 0] * inv; t.y = acc[i * 4 + 1] * inv;
    t.z = acc[i * 4 + 2] * inv; t.w = acc[i * 4 + 3] * inv;
    *(f32x4*)(op + i * 4) = t;
  }
}

extern "C" void kernel_launch(void* const* d_in, const int* in_sizes, int n_in,
                              void* d_out, int out_size, void* d_ws, size_t ws_size,
                              hipStream_t stream) {
  const float* Q = (const float*)d_in[0];
  const float* K = (const float*)d_in[1];
  const float* V = (const float*)d_in[2];
  const int* mask = (const int*)d_in[3];
  float* out = (float*)d_out;
  dim3 grid(N_ / 256, B_ * H_);
  dim3 block(256);
  attn_f32<<<grid, block, 0, stream>>>(Q, K, V, mask, out);
}

// Round 9
// 452.832 us; speedup vs baseline: 4.9775x; 4.9775x over previous
//
#include <hip/hip_runtime.h>

typedef __attribute__((ext_vector_type(8))) short short8;
typedef __attribute__((ext_vector_type(16))) float f32x16;
typedef __attribute__((ext_vector_type(4))) float f32x4;
typedef unsigned int u32;
typedef unsigned short u16;

#define B_ 8
#define H_ 8
#define N_ 2048
#define D_ 64
#define PSTR 72   // LDS row stride (elems): 64 data + 8 pad, keeps 16B align

// f32 -> bf16 round-to-nearest-even
static __device__ inline u16 bfhi(float x) {
  u32 u = __float_as_uint(x);
  return (u16)((u + 0x7FFFu + ((u >> 16) & 1u)) >> 16);
}

__global__ __launch_bounds__(256, 3) void attn_mfma(
    const float* __restrict__ Qg, const float* __restrict__ Kg,
    const float* __restrict__ Vg, const int* __restrict__ maskg,
    float* __restrict__ Og)
{
  const int qtile = blockIdx.x;   // 0..31 (64 q-rows each)
  const int bh    = blockIdx.y;   // 0..63
  const int b     = bh >> 3;      // H == 8
  const int tid   = threadIdx.x;
  const int w     = tid >> 6;
  const int lane  = tid & 63;
  const int l32   = lane & 31;
  const int hl    = lane >> 5;    // half-of-wave
  const int qh    = w >> 1;       // q-half this wave owns (rows qh*32..+32)
  const int kh    = w & 1;        // key-half (QK) / d-half (PV)

  // All LDS arrays are 'short' so vector (short8) and scalar accesses share
  // one type — no TBAA reordering hazards (R6 lesson); cross-phase accesses
  // are additionally separated by __syncthreads.
  __shared__ short sKh[64 * PSTR], sKl[64 * PSTR];   // [key][d]  hi/lo bf16
  __shared__ short sVh[64 * PSTR], sVl[64 * PSTR];   // [d][key]  hi/lo bf16
  __shared__ short sP [64 * PSTR];                   // [q][key]  bf16
  __shared__ float sM[64];

  // ---- Q fragments (A-layout: m=l32, k=hl*8+j per 16-step), split hi/lo ----
  short8 qfh[4], qfl[4];
  {
    const float* qp = Qg + ((size_t)bh * N_ + qtile * 64 + qh * 32 + l32) * D_ + hl * 8;
#pragma unroll
    for (int s = 0; s < 4; ++s) {
      f32x4 a = *(const f32x4*)(qp + s * 16);
      f32x4 c = *(const f32x4*)(qp + s * 16 + 4);
#pragma unroll
      for (int j = 0; j < 4; ++j) {
        u16 h0 = bfhi(a[j]);
        qfh[s][j] = (short)h0;
        qfl[s][j] = (short)bfhi(a[j] - __uint_as_float((u32)h0 << 16));
        u16 h1 = bfhi(c[j]);
        qfh[s][j + 4] = (short)h1;
        qfl[s][j + 4] = (short)bfhi(c[j] - __uint_as_float((u32)h1 << 16));
      }
    }
  }

  // ones B-fragment: B[k][n] = (n==0) ? 1.0bf16 : 0  -> den lands in C col 0
  short8 ones;
#pragma unroll
  for (int j = 0; j < 8; ++j) ones[j] = (short)((l32 == 0) ? 0x3F80 : 0);

  f32x16 accO, accD;
#pragma unroll
  for (int i = 0; i < 16; ++i) { accO[i] = 0.f; accD[i] = 0.f; }

  const size_t kvbase = (size_t)bh * N_ * D_;

  for (int kt = 0; kt < N_ / 64; ++kt) {
    const int k0 = kt * 64;
    __syncthreads();   // previous tile's LDS reads complete

    // ---- stage K (row-major, split): thread -> key row tid>>2, 16 floats ----
    {
      const int row = tid >> 2, seg = tid & 3;
      const float* kp = Kg + kvbase + (size_t)(k0 + row) * D_ + seg * 16;
      short8 h0, h1, l0, l1;
#pragma unroll
      for (int i2 = 0; i2 < 2; ++i2) {
        f32x4 t0 = *(const f32x4*)(kp + i2 * 8);
        f32x4 t1 = *(const f32x4*)(kp + i2 * 8 + 4);
#pragma unroll
        for (int j = 0; j < 4; ++j) {
          u16 ha = bfhi(t0[j]);
          u16 la = bfhi(t0[j] - __uint_as_float((u32)ha << 16));
          u16 hb = bfhi(t1[j]);
          u16 lb = bfhi(t1[j] - __uint_as_float((u32)hb << 16));
          if (i2 == 0) { h0[j] = (short)ha; l0[j] = (short)la; h0[j+4] = (short)hb; l0[j+4] = (short)lb; }
          else         { h1[j] = (short)ha; l1[j] = (short)la; h1[j+4] = (short)hb; l1[j+4] = (short)lb; }
        }
      }
      *(short8*)&sKh[row * PSTR + seg * 16]     = h0;
      *(short8*)&sKh[row * PSTR + seg * 16 + 8] = h1;
      *(short8*)&sKl[row * PSTR + seg * 16]     = l0;
      *(short8*)&sKl[row * PSTR + seg * 16 + 8] = l1;
    }

    // ---- stage V transposed ([d][key], split): wave w -> keys w*16..+16,
    //      lane = d; coalesced row loads, contiguous column b128 writes ----
    {
      const float* vp = Vg + kvbase + (size_t)(k0 + w * 16) * D_ + lane;
      float vv[16];
#pragma unroll
      for (int kk = 0; kk < 16; ++kk) vv[kk] = vp[(size_t)kk * D_];
      short8 h0, h1, l0, l1;
#pragma unroll
      for (int kk = 0; kk < 8; ++kk) {
        u16 ha = bfhi(vv[kk]);
        h0[kk] = (short)ha;
        l0[kk] = (short)bfhi(vv[kk] - __uint_as_float((u32)ha << 16));
        u16 hb = bfhi(vv[kk + 8]);
        h1[kk] = (short)hb;
        l1[kk] = (short)bfhi(vv[kk + 8] - __uint_as_float((u32)hb << 16));
      }
      *(short8*)&sVh[lane * PSTR + w * 16]     = h0;
      *(short8*)&sVh[lane * PSTR + w * 16 + 8] = h1;
      *(short8*)&sVl[lane * PSTR + w * 16]     = l0;
      *(short8*)&sVl[lane * PSTR + w * 16 + 8] = l1;
    }
    if (tid < 64) sM[tid] = maskg[b * N_ + k0 + tid] ? 0.f : 1.f;  // True = masked
    __syncthreads();

    // ---- S = Q K^T (3-way split, 32x32 tile per wave) ----
    f32x16 S;
#pragma unroll
    for (int i = 0; i < 16; ++i) S[i] = 0.f;
#pragma unroll
    for (int s = 0; s < 4; ++s) {
      const int off = (kh * 32 + l32) * PSTR + s * 16 + hl * 8;
      short8 kfh = *(const short8*)&sKh[off];
      short8 kfl = *(const short8*)&sKl[off];
      S = __builtin_amdgcn_mfma_f32_32x32x16_bf16(qfh[s], kfh, S, 0, 0, 0);
      S = __builtin_amdgcn_mfma_f32_32x32x16_bf16(qfl[s], kfh, S, 0, 0, 0);
      S = __builtin_amdgcn_mfma_f32_32x32x16_bf16(qfh[s], kfl, S, 0, 0, 0);
    }

    // ---- softmax numerator: p = exp(10*tanh(dot/8) - 10) in (0,1] ----
    const float pm = sM[kh * 32 + l32];
#pragma unroll
    for (int r = 0; r < 16; ++r) {
      float x  = S[r] * 0.125f;
      float ax = fminf(fabsf(x), 30.f);
      float z  = __builtin_amdgcn_exp2f(ax * -2.8853900817779268f);   // e^{-2ax}
      float nu = (x >= 0.f) ? z : 1.f;
      float e  = nu * __builtin_amdgcn_rcpf(1.f + z) * -28.853900817779268f;
      float p  = __builtin_amdgcn_exp2f(e) * pm;
      const int row = qh * 32 + (r & 3) + 8 * (r >> 2) + 4 * hl;  // C-layout row
      sP[row * PSTR + kh * 32 + l32] = (short)bfhi(p);
    }
    __syncthreads();   // P visible to all waves

    // ---- O += P V (V split); den += P * ones ----
#pragma unroll
    for (int s = 0; s < 4; ++s) {
      short8 pf  = *(const short8*)&sP[(qh * 32 + l32) * PSTR + s * 16 + hl * 8];
      const int voff = (kh * 32 + l32) * PSTR + s * 16 + hl * 8;
      short8 vfh = *(const short8*)&sVh[voff];
      short8 vfl = *(const short8*)&sVl[voff];
      accO = __builtin_amdgcn_mfma_f32_32x32x16_bf16(pf, vfh, accO, 0, 0, 0);
      accO = __builtin_amdgcn_mfma_f32_32x32x16_bf16(pf, vfl, accO, 0, 0, 0);
      accD = __builtin_amdgcn_mfma_f32_32x32x16_bf16(pf, ones, accD, 0, 0, 0);
    }
  }

  // ---- normalize and store (den for my row sits in col 0 = lane hl*32) ----
  const size_t obase = (size_t)bh * N_ + qtile * 64 + qh * 32;
#pragma unroll
  for (int r = 0; r < 16; ++r) {
    float den = __shfl(accD[r], lane & 32);
    float inv = (den > 0.f) ? (1.f / den) : 0.f;
    const int row = (r & 3) + 8 * (r >> 2) + 4 * hl;
    Og[(obase + row) * D_ + kh * 32 + l32] = accO[r] * inv;
  }
}

extern "C" void kernel_launch(void* const* d_in, const int* in_sizes, int n_in,
                              void* d_out, int out_size, void* d_ws, size_t ws_size,
                              hipStream_t stream) {
  const float* Q = (const float*)d_in[0];
  const float* K = (const float*)d_in[1];
  const float* V = (const float*)d_in[2];
  const int* mask = (const int*)d_in[3];
  float* out = (float*)d_out;
  dim3 grid(N_ / 64, B_ * H_);
  dim3 block(256);
  attn_mfma<<<grid, block, 0, stream>>>(Q, K, V, mask, out);
}

// Round 10
// 423.452 us; speedup vs baseline: 5.3228x; 1.0694x over previous
//
#include <hip/hip_runtime.h>

typedef __attribute__((ext_vector_type(8))) short short8;
typedef __attribute__((ext_vector_type(16))) float f32x16;
typedef __attribute__((ext_vector_type(4))) float f32x4;
typedef __attribute__((ext_vector_type(4))) unsigned short u16x4;
typedef __attribute__((ext_vector_type(8))) unsigned short u16x8;
typedef unsigned int u32;
typedef unsigned short u16;

#define B_ 8
#define H_ 8
#define N_ 2048
#define D_ 64
#define PSTR 72   // LDS row stride (shorts): 64 data + 8 pad (16B-aligned rows)
#define ELEMS 8388608          // B*H*N*D
#define WS_NEED (4u * 16777216u)  // Khi,Klo,VThi,VTlo @ 16 MiB each

// f32 -> bf16 round-to-nearest-even
static __device__ inline u16 bfhi(float x) {
  u32 u = __float_as_uint(x);
  return (u16)((u + 0x7FFFu + ((u >> 16) & 1u)) >> 16);
}
static __device__ inline float bf2f(u16 h) { return __uint_as_float((u32)h << 16); }

// ---------------- pre-pass 1: K -> (hi, lo) bf16, same layout ----------------
__global__ __launch_bounds__(256) void conv_k(const float* __restrict__ K,
                                              u16* __restrict__ hi,
                                              u16* __restrict__ lo) {
  const int i = (blockIdx.x * 256 + threadIdx.x) * 4;
  f32x4 v = *(const f32x4*)(K + i);
  u16x4 h, l;
#pragma unroll
  for (int j = 0; j < 4; ++j) {
    h[j] = bfhi(v[j]);
    l[j] = bfhi(v[j] - bf2f(h[j]));
  }
  *(u16x4*)&hi[i] = h;
  *(u16x4*)&lo[i] = l;
}

// ------------- pre-pass 2: V -> transposed [bh][d][key] (hi, lo) -------------
__global__ __launch_bounds__(256) void conv_vt(const float* __restrict__ V,
                                               u16* __restrict__ hi,
                                               u16* __restrict__ lo) {
  const int kt = blockIdx.x;   // 0..31
  const int bh = blockIdx.y;   // 0..63
  const int tid = threadIdx.x;
  __shared__ float sT[64 * 68];
  const size_t ib = (size_t)bh * N_ * D_ + (size_t)kt * 64 * D_;
#pragma unroll
  for (int cc = 0; cc < 4; ++cc) {
    const int c = tid + cc * 256;          // 0..1023
    const int row = c >> 4, seg = c & 15;  // 16 float4 per 64-f row
    *(f32x4*)&sT[row * 68 + seg * 4] = *(const f32x4*)(V + ib + row * D_ + seg * 4);
  }
  __syncthreads();
  const int d = tid >> 2, ks = tid & 3;    // 16 keys per thread
  u16x8 h0, h1, l0, l1;
#pragma unroll
  for (int i = 0; i < 8; ++i) {
    float a = sT[(ks * 16 + i) * 68 + d];
    h0[i] = bfhi(a); l0[i] = bfhi(a - bf2f(h0[i]));
    float c2 = sT[(ks * 16 + i + 8) * 68 + d];
    h1[i] = bfhi(c2); l1[i] = bfhi(c2 - bf2f(h1[i]));
  }
  const size_t ob = (size_t)bh * D_ * N_ + (size_t)d * N_ + kt * 64 + ks * 16;
  *(u16x8*)&hi[ob] = h0; *(u16x8*)&hi[ob + 8] = h1;
  *(u16x8*)&lo[ob] = l0; *(u16x8*)&lo[ob + 8] = l1;
}

// ------------------------------- main kernel --------------------------------
__global__ __launch_bounds__(256, 4) void attn_mfma2(
    const float* __restrict__ Qg,
    const u16* __restrict__ Khi, const u16* __restrict__ Klo,
    const u16* __restrict__ VThi, const u16* __restrict__ VTlo,
    const int* __restrict__ maskg, float* __restrict__ Og)
{
  const int qtile = blockIdx.x;   // 0..31 (64 q-rows each)
  const int bh    = blockIdx.y;   // 0..63
  const int b     = bh >> 3;      // H == 8
  const int tid   = threadIdx.x;
  const int w     = tid >> 6;
  const int lane  = tid & 63;
  const int l32   = lane & 31;
  const int hl    = lane >> 5;
  const int qh    = w >> 1;       // q-half (rows qh*32..+32)
  const int kh    = w & 1;        // key-half (QK) / d-half (PV)

  __shared__ short sKh[64 * PSTR], sKl[64 * PSTR];   // [key][d]
  __shared__ short sVh[64 * PSTR], sVl[64 * PSTR];   // [d][key]
  __shared__ float sM[64];
  short* sP = sKh;   // overlay: sKh dead after QK phase (barrier-protected)

  // ---- Q fragments (A-layout: m=l32, k=hl*8+j per 16-step), split hi/lo ----
  short8 qfh[4], qfl[4];
  {
    const float* qp = Qg + ((size_t)bh * N_ + qtile * 64 + qh * 32 + l32) * D_ + hl * 8;
#pragma unroll
    for (int s = 0; s < 4; ++s) {
      f32x4 a = *(const f32x4*)(qp + s * 16);
      f32x4 c = *(const f32x4*)(qp + s * 16 + 4);
#pragma unroll
      for (int j = 0; j < 4; ++j) {
        u16 h0 = bfhi(a[j]);
        qfh[s][j] = (short)h0;
        qfl[s][j] = (short)bfhi(a[j] - bf2f(h0));
        u16 h1 = bfhi(c[j]);
        qfh[s][j + 4] = (short)h1;
        qfl[s][j + 4] = (short)bfhi(c[j] - bf2f(h1));
      }
    }
  }

  // ones B-fragment: B[k][n] = (n==0) ? 1 : 0 -> row-sum lands in C col 0
  short8 ones;
#pragma unroll
  for (int j = 0; j < 8; ++j) ones[j] = (short)((l32 == 0) ? 0x3F80 : 0);

  f32x16 accO, accD;
#pragma unroll
  for (int i = 0; i < 16; ++i) { accO[i] = 0.f; accD[i] = 0.f; }

  const size_t kvb = (size_t)bh * N_ * D_;   // == bh*D_*N_ for VT too

  for (int kt = 0; kt < N_ / 64; ++kt) {
    const int k0 = kt * 64;
    __syncthreads();   // (A) prev tile's PV reads (incl. sP=sKh) complete

    // ---- staging: pure 16B copies, zero conversion VALU ----
#pragma unroll
    for (int cc = 0; cc < 2; ++cc) {
      const int c = tid + cc * 256;        // 0..511
      const int row = c >> 3, seg = c & 7;
      const int lofs = row * PSTR + seg * 8;
      const size_t kofs = kvb + (size_t)(k0 + row) * D_ + seg * 8;
      *(short8*)&sKh[lofs] = *(const short8*)&Khi[kofs];
      *(short8*)&sKl[lofs] = *(const short8*)&Klo[kofs];
      const size_t vofs = kvb + (size_t)row * N_ + k0 + seg * 8;
      *(short8*)&sVh[lofs] = *(const short8*)&VThi[vofs];
      *(short8*)&sVl[lofs] = *(const short8*)&VTlo[vofs];
    }
    if (tid < 64) sM[tid] = maskg[b * N_ + k0 + tid] ? -16384.f : 0.f;  // exp2 bias
    __syncthreads();   // (B) staging visible

    // ---- S = Q K^T (3-way split, 32x32 tile per wave) ----
    f32x16 S;
#pragma unroll
    for (int i = 0; i < 16; ++i) S[i] = 0.f;
#pragma unroll
    for (int s = 0; s < 4; ++s) {
      const int off = (kh * 32 + l32) * PSTR + s * 16 + hl * 8;
      short8 kfh = *(const short8*)&sKh[off];
      short8 kfl = *(const short8*)&sKl[off];
      S = __builtin_amdgcn_mfma_f32_32x32x16_bf16(qfh[s], kfh, S, 0, 0, 0);
      S = __builtin_amdgcn_mfma_f32_32x32x16_bf16(qfl[s], kfh, S, 0, 0, 0);
      S = __builtin_amdgcn_mfma_f32_32x32x16_bf16(qfh[s], kfl, S, 0, 0, 0);
    }
    __syncthreads();   // (C) all waves' QK reads of sKh/sKl complete

    // ---- softmax numerator: p = exp(10*tanh(s/8) - 10) in (0,1] ----
    // e^{-2|x|} with x=s/8 -> 2^{-|s|*log2e/4}; for s>=0: e=-c*z/(1+z),
    // s<0: e=-c/(1+z), c=20*log2e. Mask folds in as exp2 bias (-16384 -> 0).
    const float bias = sM[kh * 32 + l32];
#pragma unroll
    for (int r = 0; r < 16; ++r) {
      float s  = S[r];
      float ax = fminf(fabsf(s), 240.f);
      float z  = __builtin_amdgcn_exp2f(ax * -0.36067376022224087f);
      float nu = (s >= 0.f) ? z : 1.f;
      float rr = __builtin_amdgcn_rcpf(1.f + z);
      float e  = __builtin_fmaf(nu * rr, -28.853900817779268f, bias);
      float p  = __builtin_amdgcn_exp2f(e);
      const int row = qh * 32 + (r & 3) + 8 * (r >> 2) + 4 * hl;  // C-layout row
      sP[row * PSTR + kh * 32 + l32] = (short)((__float_as_uint(p) + 0x8000u) >> 16);
    }
    __syncthreads();   // (D) P visible

    // ---- O += P V (V split); den += P * ones ----
#pragma unroll
    for (int s = 0; s < 4; ++s) {
      short8 pf  = *(const short8*)&sP[(qh * 32 + l32) * PSTR + s * 16 + hl * 8];
      const int voff = (kh * 32 + l32) * PSTR + s * 16 + hl * 8;
      short8 vfh = *(const short8*)&sVh[voff];
      short8 vfl = *(const short8*)&sVl[voff];
      accO = __builtin_amdgcn_mfma_f32_32x32x16_bf16(pf, vfh, accO, 0, 0, 0);
      accO = __builtin_amdgcn_mfma_f32_32x32x16_bf16(pf, vfl, accO, 0, 0, 0);
      accD = __builtin_amdgcn_mfma_f32_32x32x16_bf16(pf, ones, accD, 0, 0, 0);
    }
  }

  // ---- normalize and store (row r's den sits at col 0 = lane hl*32) ----
  const size_t obase = (size_t)bh * N_ + qtile * 64 + qh * 32;
#pragma unroll
  for (int r = 0; r < 16; ++r) {
    float den = __shfl(accD[r], lane & 32);
    float inv = (den > 0.f) ? (1.f / den) : 0.f;
    const int row = (r & 3) + 8 * (r >> 2) + 4 * hl;
    Og[(obase + row) * D_ + kh * 32 + l32] = accO[r] * inv;
  }
}

// --------------- fallback (R9, proven): in-kernel conversions ---------------
__global__ __launch_bounds__(256, 3) void attn_mfma(
    const float* __restrict__ Qg, const float* __restrict__ Kg,
    const float* __restrict__ Vg, const int* __restrict__ maskg,
    float* __restrict__ Og)
{
  const int qtile = blockIdx.x;
  const int bh    = blockIdx.y;
  const int b     = bh >> 3;
  const int tid   = threadIdx.x;
  const int w     = tid >> 6;
  const int lane  = tid & 63;
  const int l32   = lane & 31;
  const int hl    = lane >> 5;
  const int qh    = w >> 1;
  const int kh    = w & 1;

  __shared__ short sKh[64 * PSTR], sKl[64 * PSTR];
  __shared__ short sVh[64 * PSTR], sVl[64 * PSTR];
  __shared__ short sP [64 * PSTR];
  __shared__ float sM[64];

  short8 qfh[4], qfl[4];
  {
    const float* qp = Qg + ((size_t)bh * N_ + qtile * 64 + qh * 32 + l32) * D_ + hl * 8;
#pragma unroll
    for (int s = 0; s < 4; ++s) {
      f32x4 a = *(const f32x4*)(qp + s * 16);
      f32x4 c = *(const f32x4*)(qp + s * 16 + 4);
#pragma unroll
      for (int j = 0; j < 4; ++j) {
        u16 h0 = bfhi(a[j]);
        qfh[s][j] = (short)h0;
        qfl[s][j] = (short)bfhi(a[j] - bf2f(h0));
        u16 h1 = bfhi(c[j]);
        qfh[s][j + 4] = (short)h1;
        qfl[s][j + 4] = (short)bfhi(c[j] - bf2f(h1));
      }
    }
  }
  short8 ones;
#pragma unroll
  for (int j = 0; j < 8; ++j) ones[j] = (short)((l32 == 0) ? 0x3F80 : 0);
  f32x16 accO, accD;
#pragma unroll
  for (int i = 0; i < 16; ++i) { accO[i] = 0.f; accD[i] = 0.f; }
  const size_t kvbase = (size_t)bh * N_ * D_;

  for (int kt = 0; kt < N_ / 64; ++kt) {
    const int k0 = kt * 64;
    __syncthreads();
    {
      const int row = tid >> 2, seg = tid & 3;
      const float* kp = Kg + kvbase + (size_t)(k0 + row) * D_ + seg * 16;
      short8 h0, h1, l0, l1;
#pragma unroll
      for (int i2 = 0; i2 < 2; ++i2) {
        f32x4 t0 = *(const f32x4*)(kp + i2 * 8);
        f32x4 t1 = *(const f32x4*)(kp + i2 * 8 + 4);
#pragma unroll
        for (int j = 0; j < 4; ++j) {
          u16 ha = bfhi(t0[j]); u16 la = bfhi(t0[j] - bf2f(ha));
          u16 hb = bfhi(t1[j]); u16 lb = bfhi(t1[j] - bf2f(hb));
          if (i2 == 0) { h0[j]=(short)ha; l0[j]=(short)la; h0[j+4]=(short)hb; l0[j+4]=(short)lb; }
          else         { h1[j]=(short)ha; l1[j]=(short)la; h1[j+4]=(short)hb; l1[j+4]=(short)lb; }
        }
      }
      *(short8*)&sKh[row * PSTR + seg * 16]     = h0;
      *(short8*)&sKh[row * PSTR + seg * 16 + 8] = h1;
      *(short8*)&sKl[row * PSTR + seg * 16]     = l0;
      *(short8*)&sKl[row * PSTR + seg * 16 + 8] = l1;
    }
    {
      const float* vp = Vg + kvbase + (size_t)(k0 + w * 16) * D_ + lane;
      float vv[16];
#pragma unroll
      for (int kk = 0; kk < 16; ++kk) vv[kk] = vp[(size_t)kk * D_];
      short8 h0, h1, l0, l1;
#pragma unroll
      for (int kk = 0; kk < 8; ++kk) {
        u16 ha = bfhi(vv[kk]);     h0[kk]=(short)ha; l0[kk]=(short)bfhi(vv[kk]-bf2f(ha));
        u16 hb = bfhi(vv[kk + 8]); h1[kk]=(short)hb; l1[kk]=(short)bfhi(vv[kk+8]-bf2f(hb));
      }
      *(short8*)&sVh[lane * PSTR + w * 16]     = h0;
      *(short8*)&sVh[lane * PSTR + w * 16 + 8] = h1;
      *(short8*)&sVl[lane * PSTR + w * 16]     = l0;
      *(short8*)&sVl[lane * PSTR + w * 16 + 8] = l1;
    }
    if (tid < 64) sM[tid] = maskg[b * N_ + k0 + tid] ? 0.f : 1.f;
    __syncthreads();

    f32x16 S;
#pragma unroll
    for (int i = 0; i < 16; ++i) S[i] = 0.f;
#pragma unroll
    for (int s = 0; s < 4; ++s) {
      const int off = (kh * 32 + l32) * PSTR + s * 16 + hl * 8;
      short8 kfh = *(const short8*)&sKh[off];
      short8 kfl = *(const short8*)&sKl[off];
      S = __builtin_amdgcn_mfma_f32_32x32x16_bf16(qfh[s], kfh, S, 0, 0, 0);
      S = __builtin_amdgcn_mfma_f32_32x32x16_bf16(qfl[s], kfh, S, 0, 0, 0);
      S = __builtin_amdgcn_mfma_f32_32x32x16_bf16(qfh[s], kfl, S, 0, 0, 0);
    }
    const float pm = sM[kh * 32 + l32];
#pragma unroll
    for (int r = 0; r < 16; ++r) {
      float x  = S[r] * 0.125f;
      float ax = fminf(fabsf(x), 30.f);
      float z  = __builtin_amdgcn_exp2f(ax * -2.8853900817779268f);
      float nu = (x >= 0.f) ? z : 1.f;
      float e  = nu * __builtin_amdgcn_rcpf(1.f + z) * -28.853900817779268f;
      float p  = __builtin_amdgcn_exp2f(e) * pm;
      const int row = qh * 32 + (r & 3) + 8 * (r >> 2) + 4 * hl;
      sP[row * PSTR + kh * 32 + l32] = (short)bfhi(p);
    }
    __syncthreads();
#pragma unroll
    for (int s = 0; s < 4; ++s) {
      short8 pf  = *(const short8*)&sP[(qh * 32 + l32) * PSTR + s * 16 + hl * 8];
      const int voff = (kh * 32 + l32) * PSTR + s * 16 + hl * 8;
      short8 vfh = *(const short8*)&sVh[voff];
      short8 vfl = *(const short8*)&sVl[voff];
      accO = __builtin_amdgcn_mfma_f32_32x32x16_bf16(pf, vfh, accO, 0, 0, 0);
      accO = __builtin_amdgcn_mfma_f32_32x32x16_bf16(pf, vfl, accO, 0, 0, 0);
      accD = __builtin_amdgcn_mfma_f32_32x32x16_bf16(pf, ones, accD, 0, 0, 0);
    }
  }
  const size_t obase = (size_t)bh * N_ + qtile * 64 + qh * 32;
#pragma unroll
  for (int r = 0; r < 16; ++r) {
    float den = __shfl(accD[r], lane & 32);
    float inv = (den > 0.f) ? (1.f / den) : 0.f;
    const int row = (r & 3) + 8 * (r >> 2) + 4 * hl;
    Og[(obase + row) * D_ + kh * 32 + l32] = accO[r] * inv;
  }
}

extern "C" void kernel_launch(void* const* d_in, const int* in_sizes, int n_in,
                              void* d_out, int out_size, void* d_ws, size_t ws_size,
                              hipStream_t stream) {
  const float* Q = (const float*)d_in[0];
  const float* K = (const float*)d_in[1];
  const float* V = (const float*)d_in[2];
  const int* mask = (const int*)d_in[3];
  float* out = (float*)d_out;
  dim3 grid(N_ / 64, B_ * H_);
  dim3 block(256);
  if (ws_size >= (size_t)WS_NEED) {
    u16* w    = (u16*)d_ws;
    u16* Khi  = w;
    u16* Klo  = w + ELEMS;
    u16* VThi = w + 2 * (size_t)ELEMS;
    u16* VTlo = w + 3 * (size_t)ELEMS;
    conv_k <<<dim3(ELEMS / 1024), block, 0, stream>>>(K, Khi, Klo);
    conv_vt<<<dim3(32, 64), block, 0, stream>>>(V, VThi, VTlo);
    attn_mfma2<<<grid, block, 0, stream>>>(Q, Khi, Klo, VThi, VTlo, mask, out);
  } else {
    attn_mfma<<<grid, block, 0, stream>>>(Q, K, V, mask, out);
  }
}

// Round 11
// 409.232 us; speedup vs baseline: 5.5078x; 1.0347x over previous
//
#include <hip/hip_runtime.h>

typedef __attribute__((ext_vector_type(8))) short short8;
typedef __attribute__((ext_vector_type(16))) float f32x16;
typedef __attribute__((ext_vector_type(4))) float f32x4;
typedef __attribute__((ext_vector_type(4))) unsigned short u16x4;
typedef __attribute__((ext_vector_type(8))) unsigned short u16x8;
typedef unsigned int u32;
typedef unsigned short u16;

#define B_ 8
#define H_ 8
#define N_ 2048
#define D_ 64
#define PSTR 72   // LDS row stride (shorts)
#define ELEMS 8388608             // B*H*N*D
#define WS_NEED (4ull * 16777216ull)

static __device__ inline u16 bfhi(float x) {
  u32 u = __float_as_uint(x);
  return (u16)((u + 0x7FFFu + ((u >> 16) & 1u)) >> 16);
}
static __device__ inline float bf2f(u16 h) { return __uint_as_float((u32)h << 16); }

// ---- fused prepass: K -> (hi,lo) same layout; V -> [bh][d][key] (hi,lo) ----
__global__ __launch_bounds__(256) void conv_kv(
    const float* __restrict__ K, const float* __restrict__ V,
    u16* __restrict__ Khi, u16* __restrict__ Klo,
    u16* __restrict__ VThi, u16* __restrict__ VTlo) {
  const int kt = blockIdx.x, bh = blockIdx.y, tid = threadIdx.x;
  const size_t ib = (size_t)bh * N_ * D_ + (size_t)kt * 64 * D_;
  __shared__ float sT[64 * 68];
#pragma unroll
  for (int cc = 0; cc < 4; ++cc) {
    const int c = tid + cc * 256, row = c >> 4, seg = c & 15;
    f32x4 kv = *(const f32x4*)(K + ib + row * D_ + seg * 4);
    u16x4 h, l;
#pragma unroll
    for (int j = 0; j < 4; ++j) { h[j] = bfhi(kv[j]); l[j] = bfhi(kv[j] - bf2f(h[j])); }
    *(u16x4*)&Khi[ib + row * D_ + seg * 4] = h;
    *(u16x4*)&Klo[ib + row * D_ + seg * 4] = l;
    *(f32x4*)&sT[row * 68 + seg * 4] = *(const f32x4*)(V + ib + row * D_ + seg * 4);
  }
  __syncthreads();
  const int d = tid >> 2, ks = tid & 3;   // 16 keys per thread, fixed d
  u16x8 h0, h1, l0, l1;
#pragma unroll
  for (int i = 0; i < 8; ++i) {
    float a = sT[(ks * 16 + i) * 68 + d];
    h0[i] = bfhi(a); l0[i] = bfhi(a - bf2f(h0[i]));
    float c2 = sT[(ks * 16 + i + 8) * 68 + d];
    h1[i] = bfhi(c2); l1[i] = bfhi(c2 - bf2f(h1[i]));
  }
  const size_t ob = (size_t)bh * D_ * N_ + (size_t)d * N_ + kt * 64 + ks * 16;
  *(u16x8*)&VThi[ob] = h0; *(u16x8*)&VThi[ob + 8] = h1;
  *(u16x8*)&VTlo[ob] = l0; *(u16x8*)&VTlo[ob + 8] = l1;
}

// -------------------- main kernel: 128 q-rows per block ---------------------
__global__ __launch_bounds__(256, 4) void attn_mfma3(
    const float* __restrict__ Qg,
    const u16* __restrict__ Khi, const u16* __restrict__ Klo,
    const u16* __restrict__ VThi, const u16* __restrict__ VTlo,
    const int* __restrict__ maskg, float* __restrict__ Og)
{
  const int qtile = blockIdx.x;   // 0..15 (128 q-rows each)
  const int bh = blockIdx.y, b = bh >> 3;
  const int tid = threadIdx.x, w = tid >> 6, lane = tid & 63;
  const int l32 = lane & 31, hl = lane >> 5;

  __shared__ short sKbuf[2 * 64 * PSTR];          // sKh | sKl ; sP overlays
  __shared__ short sVh[64 * PSTR], sVl[64 * PSTR];
  __shared__ float sM[64];
  short* const sKh = sKbuf;
  short* const sKl = sKbuf + 64 * PSTR;
  short* const sP  = sKbuf;                       // 128*PSTR == 2*64*PSTR

  // ---- Q fragments for my 32 q-rows (A: m=l32, k=s*16+hl*8+j), hi/lo ----
  short8 qfh[4], qfl[4];
  {
    const float* qp = Qg + ((size_t)bh * N_ + qtile * 128 + w * 32 + l32) * D_ + hl * 8;
#pragma unroll
    for (int s = 0; s < 4; ++s) {
      f32x4 a = *(const f32x4*)(qp + s * 16);
      f32x4 c = *(const f32x4*)(qp + s * 16 + 4);
#pragma unroll
      for (int j = 0; j < 4; ++j) {
        u16 h0 = bfhi(a[j]); qfh[s][j] = (short)h0; qfl[s][j] = (short)bfhi(a[j] - bf2f(h0));
        u16 h1 = bfhi(c[j]); qfh[s][j+4] = (short)h1; qfl[s][j+4] = (short)bfhi(c[j] - bf2f(h1));
      }
    }
  }
  short8 ones;
#pragma unroll
  for (int j = 0; j < 8; ++j) ones[j] = (short)((l32 == 0) ? 0x3F80 : 0);

  f32x16 accO0, accO1, accD;
#pragma unroll
  for (int i = 0; i < 16; ++i) { accO0[i] = 0.f; accO1[i] = 0.f; accD[i] = 0.f; }

  const size_t kvb = (size_t)bh * N_ * D_;

  for (int kt = 0; kt < N_ / 64; ++kt) {
    const int k0 = kt * 64;
    __syncthreads();   // (A) prev PV reads (incl. sP overlay) complete

    // ---- staging: pure b128 copies ----
#pragma unroll
    for (int cc = 0; cc < 2; ++cc) {
      const int c = tid + cc * 256, row = c >> 3, seg = c & 7;
      const int lofs = row * PSTR + seg * 8;
      const size_t kofs = kvb + (size_t)(k0 + row) * D_ + seg * 8;
      *(short8*)&sKh[lofs] = *(const short8*)&Khi[kofs];
      *(short8*)&sKl[lofs] = *(const short8*)&Klo[kofs];
      const size_t vofs = kvb + (size_t)row * N_ + k0 + seg * 8;
      *(short8*)&sVh[lofs] = *(const short8*)&VThi[vofs];
      *(short8*)&sVl[lofs] = *(const short8*)&VTlo[vofs];
    }
    if (tid < 64) sM[tid] = maskg[b * N_ + k0 + tid] ? -16384.f : 0.f;  // exp2 bias
    __syncthreads();   // (B)

    // ---- S = Q K^T, both 32-key column halves (3-way bf16 split) ----
    f32x16 S0, S1;
#pragma unroll
    for (int i = 0; i < 16; ++i) { S0[i] = 0.f; S1[i] = 0.f; }
#pragma unroll
    for (int s = 0; s < 4; ++s) {
      const int o0 = l32 * PSTR + s * 16 + hl * 8;
      short8 kfh = *(const short8*)&sKh[o0];
      short8 kfl = *(const short8*)&sKl[o0];
      S0 = __builtin_amdgcn_mfma_f32_32x32x16_bf16(qfh[s], kfh, S0, 0, 0, 0);
      S0 = __builtin_amdgcn_mfma_f32_32x32x16_bf16(qfl[s], kfh, S0, 0, 0, 0);
      S0 = __builtin_amdgcn_mfma_f32_32x32x16_bf16(qfh[s], kfl, S0, 0, 0, 0);
      const int o1 = (32 + l32) * PSTR + s * 16 + hl * 8;
      short8 kgh = *(const short8*)&sKh[o1];
      short8 kgl = *(const short8*)&sKl[o1];
      S1 = __builtin_amdgcn_mfma_f32_32x32x16_bf16(qfh[s], kgh, S1, 0, 0, 0);
      S1 = __builtin_amdgcn_mfma_f32_32x32x16_bf16(qfl[s], kgh, S1, 0, 0, 0);
      S1 = __builtin_amdgcn_mfma_f32_32x32x16_bf16(qfh[s], kgl, S1, 0, 0, 0);
    }
    __syncthreads();   // (C) all QK reads of sK done; sP overlay now writable

    // ---- softmax numerator p = exp(10*tanh(s/8) - 10), mask as exp2 bias ----
    const float bias0 = sM[l32], bias1 = sM[32 + l32];
#pragma unroll
    for (int r = 0; r < 16; ++r) {
      const int row = w * 32 + (r & 3) + 8 * (r >> 2) + 4 * hl;  // C-layout row
      {
        float s  = S0[r];
        float z  = __builtin_amdgcn_exp2f(fabsf(s) * -0.36067376022224087f);
        float nu = (s >= 0.f) ? z : 1.f;
        float e  = __builtin_fmaf(nu * __builtin_amdgcn_rcpf(1.f + z),
                                  -28.853900817779268f, bias0);
        float p  = __builtin_amdgcn_exp2f(e);
        sP[row * PSTR + l32] = (short)((__float_as_uint(p) + 0x8000u) >> 16);
      }
      {
        float s  = S1[r];
        float z  = __builtin_amdgcn_exp2f(fabsf(s) * -0.36067376022224087f);
        float nu = (s >= 0.f) ? z : 1.f;
        float e  = __builtin_fmaf(nu * __builtin_amdgcn_rcpf(1.f + z),
                                  -28.853900817779268f, bias1);
        float p  = __builtin_amdgcn_exp2f(e);
        sP[row * PSTR + 32 + l32] = (short)((__float_as_uint(p) + 0x8000u) >> 16);
      }
    }
    __syncthreads();   // (D) P visible

    // ---- O += P V (both d-halves, V hi/lo); den += P * ones ----
#pragma unroll
    for (int s = 0; s < 4; ++s) {
      short8 pf = *(const short8*)&sP[(w * 32 + l32) * PSTR + s * 16 + hl * 8];
      const int o0 = l32 * PSTR + s * 16 + hl * 8;          // d = l32
      short8 v0h = *(const short8*)&sVh[o0];
      short8 v0l = *(const short8*)&sVl[o0];
      accO0 = __builtin_amdgcn_mfma_f32_32x32x16_bf16(pf, v0h, accO0, 0, 0, 0);
      accO0 = __builtin_amdgcn_mfma_f32_32x32x16_bf16(pf, v0l, accO0, 0, 0, 0);
      const int o1 = (32 + l32) * PSTR + s * 16 + hl * 8;   // d = 32 + l32
      short8 v1h = *(const short8*)&sVh[o1];
      short8 v1l = *(const short8*)&sVl[o1];
      accO1 = __builtin_amdgcn_mfma_f32_32x32x16_bf16(pf, v1h, accO1, 0, 0, 0);
      accO1 = __builtin_amdgcn_mfma_f32_32x32x16_bf16(pf, v1l, accO1, 0, 0, 0);
      accD  = __builtin_amdgcn_mfma_f32_32x32x16_bf16(pf, ones, accD, 0, 0, 0);
    }
  }

  // ---- normalize and store ----
  const size_t obase = (size_t)bh * N_ + qtile * 128 + w * 32;
#pragma unroll
  for (int r = 0; r < 16; ++r) {
    float den = __shfl(accD[r], lane & 32);   // col 0 of my half holds row-sum
    float inv = (den > 0.f) ? (1.f / den) : 0.f;
    const int row = (r & 3) + 8 * (r >> 2) + 4 * hl;
    Og[(obase + row) * D_ + l32]      = accO0[r] * inv;
    Og[(obase + row) * D_ + 32 + l32] = accO1[r] * inv;
  }
}

// --------------- fallback (R9, proven): in-kernel conversions ---------------
__global__ __launch_bounds__(256, 3) void attn_mfma(
    const float* __restrict__ Qg, const float* __restrict__ Kg,
    const float* __restrict__ Vg, const int* __restrict__ maskg,
    float* __restrict__ Og)
{
  const int qtile = blockIdx.x;
  const int bh    = blockIdx.y;
  const int b     = bh >> 3;
  const int tid   = threadIdx.x;
  const int w     = tid >> 6;
  const int lane  = tid & 63;
  const int l32   = lane & 31;
  const int hl    = lane >> 5;
  const int qh    = w >> 1;
  const int kh    = w & 1;

  __shared__ short sKh[64 * PSTR], sKl[64 * PSTR];
  __shared__ short sVh[64 * PSTR], sVl[64 * PSTR];
  __shared__ short sP [64 * PSTR];
  __shared__ float sM[64];

  short8 qfh[4], qfl[4];
  {
    const float* qp = Qg + ((size_t)bh * N_ + qtile * 64 + qh * 32 + l32) * D_ + hl * 8;
#pragma unroll
    for (int s = 0; s < 4; ++s) {
      f32x4 a = *(const f32x4*)(qp + s * 16);
      f32x4 c = *(const f32x4*)(qp + s * 16 + 4);
#pragma unroll
      for (int j = 0; j < 4; ++j) {
        u16 h0 = bfhi(a[j]);
        qfh[s][j] = (short)h0;
        qfl[s][j] = (short)bfhi(a[j] - bf2f(h0));
        u16 h1 = bfhi(c[j]);
        qfh[s][j + 4] = (short)h1;
        qfl[s][j + 4] = (short)bfhi(c[j] - bf2f(h1));
      }
    }
  }
  short8 ones;
#pragma unroll
  for (int j = 0; j < 8; ++j) ones[j] = (short)((l32 == 0) ? 0x3F80 : 0);
  f32x16 accO, accD;
#pragma unroll
  for (int i = 0; i < 16; ++i) { accO[i] = 0.f; accD[i] = 0.f; }
  const size_t kvbase = (size_t)bh * N_ * D_;

  for (int kt = 0; kt < N_ / 64; ++kt) {
    const int k0 = kt * 64;
    __syncthreads();
    {
      const int row = tid >> 2, seg = tid & 3;
      const float* kp = Kg + kvbase + (size_t)(k0 + row) * D_ + seg * 16;
      short8 h0, h1, l0, l1;
#pragma unroll
      for (int i2 = 0; i2 < 2; ++i2) {
        f32x4 t0 = *(const f32x4*)(kp + i2 * 8);
        f32x4 t1 = *(const f32x4*)(kp + i2 * 8 + 4);
#pragma unroll
        for (int j = 0; j < 4; ++j) {
          u16 ha = bfhi(t0[j]); u16 la = bfhi(t0[j] - bf2f(ha));
          u16 hb = bfhi(t1[j]); u16 lb = bfhi(t1[j] - bf2f(hb));
          if (i2 == 0) { h0[j]=(short)ha; l0[j]=(short)la; h0[j+4]=(short)hb; l0[j+4]=(short)lb; }
          else         { h1[j]=(short)ha; l1[j]=(short)la; h1[j+4]=(short)hb; l1[j+4]=(short)lb; }
        }
      }
      *(short8*)&sKh[row * PSTR + seg * 16]     = h0;
      *(short8*)&sKh[row * PSTR + seg * 16 + 8] = h1;
      *(short8*)&sKl[row * PSTR + seg * 16]     = l0;
      *(short8*)&sKl[row * PSTR + seg * 16 + 8] = l1;
    }
    {
      const float* vp = Vg + kvbase + (size_t)(k0 + w * 16) * D_ + lane;
      float vv[16];
#pragma unroll
      for (int kk = 0; kk < 16; ++kk) vv[kk] = vp[(size_t)kk * D_];
      short8 h0, h1, l0, l1;
#pragma unroll
      for (int kk = 0; kk < 8; ++kk) {
        u16 ha = bfhi(vv[kk]);     h0[kk]=(short)ha; l0[kk]=(short)bfhi(vv[kk]-bf2f(ha));
        u16 hb = bfhi(vv[kk + 8]); h1[kk]=(short)hb; l1[kk]=(short)bfhi(vv[kk+8]-bf2f(hb));
      }
      *(short8*)&sVh[lane * PSTR + w * 16]     = h0;
      *(short8*)&sVh[lane * PSTR + w * 16 + 8] = h1;
      *(short8*)&sVl[lane * PSTR + w * 16]     = l0;
      *(short8*)&sVl[lane * PSTR + w * 16 + 8] = l1;
    }
    if (tid < 64) sM[tid] = maskg[b * N_ + k0 + tid] ? 0.f : 1.f;
    __syncthreads();

    f32x16 S;
#pragma unroll
    for (int i = 0; i < 16; ++i) S[i] = 0.f;
#pragma unroll
    for (int s = 0; s < 4; ++s) {
      const int off = (kh * 32 + l32) * PSTR + s * 16 + hl * 8;
      short8 kfh = *(const short8*)&sKh[off];
      short8 kfl = *(const short8*)&sKl[off];
      S = __builtin_amdgcn_mfma_f32_32x32x16_bf16(qfh[s], kfh, S, 0, 0, 0);
      S = __builtin_amdgcn_mfma_f32_32x32x16_bf16(qfl[s], kfh, S, 0, 0, 0);
      S = __builtin_amdgcn_mfma_f32_32x32x16_bf16(qfh[s], kfl, S, 0, 0, 0);
    }
    const float pm = sM[kh * 32 + l32];
#pragma unroll
    for (int r = 0; r < 16; ++r) {
      float x  = S[r] * 0.125f;
      float ax = fminf(fabsf(x), 30.f);
      float z  = __builtin_amdgcn_exp2f(ax * -2.8853900817779268f);
      float nu = (x >= 0.f) ? z : 1.f;
      float e  = nu * __builtin_amdgcn_rcpf(1.f + z) * -28.853900817779268f;
      float p  = __builtin_amdgcn_exp2f(e) * pm;
      const int row = qh * 32 + (r & 3) + 8 * (r >> 2) + 4 * hl;
      sP[row * PSTR + kh * 32 + l32] = (short)bfhi(p);
    }
    __syncthreads();
#pragma unroll
    for (int s = 0; s < 4; ++s) {
      short8 pf  = *(const short8*)&sP[(qh * 32 + l32) * PSTR + s * 16 + hl * 8];
      const int voff = (kh * 32 + l32) * PSTR + s * 16 + hl * 8;
      short8 vfh = *(const short8*)&sVh[voff];
      short8 vfl = *(const short8*)&sVl[voff];
      accO = __builtin_amdgcn_mfma_f32_32x32x16_bf16(pf, vfh, accO, 0, 0, 0);
      accO = __builtin_amdgcn_mfma_f32_32x32x16_bf16(pf, vfl, accO, 0, 0, 0);
      accD = __builtin_amdgcn_mfma_f32_32x32x16_bf16(pf, ones, accD, 0, 0, 0);
    }
  }
  const size_t obase = (size_t)bh * N_ + qtile * 64 + qh * 32;
#pragma unroll
  for (int r = 0; r < 16; ++r) {
    float den = __shfl(accD[r], lane & 32);
    float inv = (den > 0.f) ? (1.f / den) : 0.f;
    const int row = (r & 3) + 8 * (r >> 2) + 4 * hl;
    Og[(obase + row) * D_ + kh * 32 + l32] = accO[r] * inv;
  }
}

extern "C" void kernel_launch(void* const* d_in, const int* in_sizes, int n_in,
                              void* d_out, int out_size, void* d_ws, size_t ws_size,
                              hipStream_t stream) {
  const float* Q = (const float*)d_in[0];
  const float* K = (const float*)d_in[1];
  const float* V = (const float*)d_in[2];
  const int* mask = (const int*)d_in[3];
  float* out = (float*)d_out;
  dim3 block(256);
  if (ws_size >= (size_t)WS_NEED) {
    u16* wsp  = (u16*)d_ws;
    u16* Khi  = wsp;
    u16* Klo  = wsp + ELEMS;
    u16* VThi = wsp + 2 * (size_t)ELEMS;
    u16* VTlo = wsp + 3 * (size_t)ELEMS;
    conv_kv<<<dim3(32, 64), block, 0, stream>>>(K, V, Khi, Klo, VThi, VTlo);
    attn_mfma3<<<dim3(16, 64), block, 0, stream>>>(Q, Khi, Klo, VThi, VTlo, mask, out);
  } else {
    attn_mfma<<<dim3(32, 64), block, 0, stream>>>(Q, K, V, mask, out);
  }
}